// Round 5
// baseline (478.871 us; speedup 1.0000x reference)
//
#include <hip/hip_runtime.h>
#include <math.h>

#define INC 128
#define HID 64

// ---------------- degree count ----------------
__global__ __launch_bounds__(256) void k_count(const int* __restrict__ ei, int E,
                                               int* __restrict__ deg) {
    int e = blockIdx.x * 256 + threadIdx.x;
    if (e < E) {
        int d = ei[E + e];  // dst row of the 2xE int32 edge_index
        atomicAdd(&deg[d], 1);
    }
}

// ---------------- scan stage 1: per-block exclusive scan (+ dinv fused) ----------------
__global__ __launch_bounds__(256) void k_scan1(const int* __restrict__ deg, int* __restrict__ excl,
                                               int* __restrict__ bsums, float* __restrict__ dinv, int n) {
    __shared__ int tmp[256];
    int i = blockIdx.x * 256 + threadIdx.x;
    int v = (i < n) ? deg[i] : 0;
    if (i < n) dinv[i] = rsqrtf((float)v + 1.0f);
    tmp[threadIdx.x] = v;
    __syncthreads();
    for (int offs = 1; offs < 256; offs <<= 1) {
        int t = (threadIdx.x >= offs) ? tmp[threadIdx.x - offs] : 0;
        __syncthreads();
        tmp[threadIdx.x] += t;
        __syncthreads();
    }
    if (i < n) excl[i] = tmp[threadIdx.x] - v;
    if (threadIdx.x == 255) bsums[blockIdx.x] = tmp[255];
}

// ---------------- scan stage 2: scan the block sums (nb <= 512) ----------------
__global__ __launch_bounds__(512) void k_scan2(int* __restrict__ bsums, int nb) {
    __shared__ int tmp[512];
    int v = (threadIdx.x < nb) ? bsums[threadIdx.x] : 0;
    tmp[threadIdx.x] = v;
    __syncthreads();
    for (int offs = 1; offs < 512; offs <<= 1) {
        int t = (threadIdx.x >= offs) ? tmp[threadIdx.x - offs] : 0;
        __syncthreads();
        tmp[threadIdx.x] += t;
        __syncthreads();
    }
    if (threadIdx.x < nb) bsums[threadIdx.x] = tmp[threadIdx.x] - v;  // exclusive
}

// ---------------- scan stage 3: add block offsets, init cursor ----------------
__global__ __launch_bounds__(256) void k_scan3(int* __restrict__ row_start, int* __restrict__ cursor,
                                               const int* __restrict__ bsums, int n, int E) {
    int i = blockIdx.x * 256 + threadIdx.x;
    if (i < n) {
        int rs = row_start[i] + bsums[blockIdx.x];
        row_start[i] = rs;
        cursor[i] = rs;
    }
    if (blockIdx.x == 0 && threadIdx.x == 0) row_start[n] = E;
}

// ---------------- CSR fill (counting-sort placement) ----------------
__global__ __launch_bounds__(256) void k_fill(const int* __restrict__ ei, int E,
                                              int* __restrict__ cursor, int* __restrict__ ssrc) {
    int e = blockIdx.x * 256 + threadIdx.x;
    if (e < E) {
        int s = ei[e];
        int d = ei[E + e];
        int p = atomicAdd(&cursor[d], 1);
        ssrc[p] = s;
    }
}

// ---------------- h' = (x @ W) * dinv[row] ----------------
// One wave = 4 rows; lane = output column (HID=64). W staged in LDS (32 KB).
__global__ __launch_bounds__(256) void k_gemm(const float* __restrict__ x, const float* __restrict__ W,
                                              const float* __restrict__ dinv, float* __restrict__ h, int n) {
    __shared__ float Ws[INC * HID];
    for (int i = threadIdx.x; i < INC * HID / 4; i += 256)
        ((float4*)Ws)[i] = ((const float4*)W)[i];
    __syncthreads();

    int wave = threadIdx.x >> 6;
    int lane = threadIdx.x & 63;
    int row0 = (blockIdx.x * 4 + wave) * 4;
    if (row0 >= n) return;

    if (row0 + 4 <= n) {
        float a0 = 0.f, a1 = 0.f, a2 = 0.f, a3 = 0.f;
        const float* xp = x + (size_t)row0 * INC;
        #pragma unroll 8
        for (int k = 0; k < INC; k += 4) {
            float4 x0 = *(const float4*)(xp + k);
            float4 x1 = *(const float4*)(xp + INC + k);
            float4 x2 = *(const float4*)(xp + 2 * INC + k);
            float4 x3 = *(const float4*)(xp + 3 * INC + k);
            float w0 = Ws[(k + 0) * HID + lane];
            float w1 = Ws[(k + 1) * HID + lane];
            float w2 = Ws[(k + 2) * HID + lane];
            float w3 = Ws[(k + 3) * HID + lane];
            a0 += x0.x * w0 + x0.y * w1 + x0.z * w2 + x0.w * w3;
            a1 += x1.x * w0 + x1.y * w1 + x1.z * w2 + x1.w * w3;
            a2 += x2.x * w0 + x2.y * w1 + x2.z * w2 + x2.w * w3;
            a3 += x3.x * w0 + x3.y * w1 + x3.z * w2 + x3.w * w3;
        }
        h[(size_t)(row0 + 0) * HID + lane] = a0 * dinv[row0 + 0];
        h[(size_t)(row0 + 1) * HID + lane] = a1 * dinv[row0 + 1];
        h[(size_t)(row0 + 2) * HID + lane] = a2 * dinv[row0 + 2];
        h[(size_t)(row0 + 3) * HID + lane] = a3 * dinv[row0 + 3];
    } else {
        for (int r = 0; r < n - row0; ++r) {
            float acc = 0.f;
            const float* xr = x + (size_t)(row0 + r) * INC;
            for (int k = 0; k < INC; ++k) acc += xr[k] * Ws[k * HID + lane];
            h[(size_t)(row0 + r) * HID + lane] = acc * dinv[row0 + r];
        }
    }
}

// ---------------- gather + self-loop + bias + PReLU ----------------
// 16 lanes per node, each lane owns a float4 chunk of the 64-wide row.
__global__ __launch_bounds__(256) void k_gather(const float* __restrict__ h, const int* __restrict__ row_start,
                                                const int* __restrict__ ssrc, const float* __restrict__ dinv,
                                                const float* __restrict__ bias, const float* __restrict__ pw,
                                                float* __restrict__ out, int n) {
    int g = blockIdx.x * 16 + (threadIdx.x >> 4);
    if (g >= n) return;
    int c = (threadIdx.x & 15) * 4;

    int e = row_start[g];
    int e1 = row_start[g + 1];
    float ax = 0.f, ay = 0.f, az = 0.f, aw = 0.f;

    if (e + 4 <= e1) {
        int s0 = ssrc[e], s1 = ssrc[e + 1], s2 = ssrc[e + 2], s3 = ssrc[e + 3];
        for (;;) {
            float4 h0 = *(const float4*)(h + (size_t)s0 * HID + c);
            float4 h1 = *(const float4*)(h + (size_t)s1 * HID + c);
            float4 h2 = *(const float4*)(h + (size_t)s2 * HID + c);
            float4 h3 = *(const float4*)(h + (size_t)s3 * HID + c);
            e += 4;
            if (e + 4 <= e1) {  // prefetch next quad's indices before the adds
                int t0 = ssrc[e], t1 = ssrc[e + 1], t2 = ssrc[e + 2], t3 = ssrc[e + 3];
                ax += (h0.x + h1.x) + (h2.x + h3.x);
                ay += (h0.y + h1.y) + (h2.y + h3.y);
                az += (h0.z + h1.z) + (h2.z + h3.z);
                aw += (h0.w + h1.w) + (h2.w + h3.w);
                s0 = t0; s1 = t1; s2 = t2; s3 = t3;
            } else {
                ax += (h0.x + h1.x) + (h2.x + h3.x);
                ay += (h0.y + h1.y) + (h2.y + h3.y);
                az += (h0.z + h1.z) + (h2.z + h3.z);
                aw += (h0.w + h1.w) + (h2.w + h3.w);
                break;
            }
        }
    }
    for (; e < e1; ++e) {
        int s = ssrc[e];
        float4 hv = *(const float4*)(h + (size_t)s * HID + c);
        ax += hv.x; ay += hv.y; az += hv.z; aw += hv.w;
    }

    float me = dinv[g];
    float4 hs = *(const float4*)(h + (size_t)g * HID + c);
    float4 bb = *(const float4*)(bias + c);
    float4 pp = *(const float4*)(pw + c);

    float vx = (ax + hs.x) * me + bb.x;
    float vy = (ay + hs.y) * me + bb.y;
    float vz = (az + hs.z) * me + bb.z;
    float vw = (aw + hs.w) * me + bb.w;

    float4 o;
    o.x = vx >= 0.f ? vx : pp.x * vx;
    o.y = vy >= 0.f ? vy : pp.y * vy;
    o.z = vz >= 0.f ? vz : pp.z * vz;
    o.w = vw >= 0.f ? vw : pp.w * vw;
    *(float4*)(out + (size_t)g * HID + c) = o;
}

extern "C" void kernel_launch(void* const* d_in, const int* in_sizes, int n_in,
                              void* d_out, int out_size, void* d_ws, size_t ws_size,
                              hipStream_t stream) {
    const float* x    = (const float*)d_in[0];
    const int*   ei   = (const int*)d_in[1];   // int32 per harness contract (2 x E)
    const float* W    = (const float*)d_in[2];
    const float* bias = (const float*)d_in[3];
    const float* pw   = (const float*)d_in[4];
    float* out        = (float*)d_out;

    int n = in_sizes[0] / INC;
    int E = in_sizes[1] / 2;

    // workspace carve-out (256B aligned regions)
    char* ws = (char*)d_ws;
    size_t off = 0;
    auto carve = [&](size_t bytes) -> void* {
        void* p = ws + off;
        off = (off + bytes + 255) & ~(size_t)255;
        return p;
    };
    float* h        = (float*)carve((size_t)n * HID * sizeof(float));
    int*   deg      = (int*)carve((size_t)n * sizeof(int));
    float* dinv     = (float*)carve((size_t)n * sizeof(float));
    int*   row_start= (int*)carve(((size_t)n + 1) * sizeof(int));
    int*   cursor   = (int*)carve((size_t)n * sizeof(int));
    int*   ssrc     = (int*)carve((size_t)E * sizeof(int));
    int    nb       = (n + 255) / 256;
    int*   bsums    = (int*)carve((size_t)nb * sizeof(int));
    (void)ws_size; (void)n_in; (void)out_size;

    int gE = (E + 255) / 256;
    int gN = nb;
    int gR = (n + 15) / 16;

    hipMemsetAsync(deg, 0, (size_t)n * sizeof(int), stream);
    k_count<<<gE, 256, 0, stream>>>(ei, E, deg);
    k_scan1<<<gN, 256, 0, stream>>>(deg, row_start, bsums, dinv, n);
    k_scan2<<<1, 512, 0, stream>>>(bsums, nb);
    k_scan3<<<gN, 256, 0, stream>>>(row_start, cursor, bsums, n, E);
    k_fill<<<gE, 256, 0, stream>>>(ei, E, cursor, ssrc);
    k_gemm<<<gR, 256, 0, stream>>>(x, W, dinv, h, n);
    k_gather<<<gR, 256, 0, stream>>>(h, row_start, ssrc, dinv, bias, pw, out, n);
}

// Round 6
// 466.427 us; speedup vs baseline: 1.0267x; 1.0267x over previous
//
#include <hip/hip_runtime.h>
#include <math.h>

#define INC 128
#define HID 64

// ---------------- degree count ----------------
__global__ __launch_bounds__(256) void k_count(const int* __restrict__ ei, int E,
                                               int* __restrict__ deg) {
    int e = blockIdx.x * 256 + threadIdx.x;
    if (e < E) {
        int d = ei[E + e];  // dst row of the 2xE int32 edge_index
        atomicAdd(&deg[d], 1);
    }
}

// ---------------- scan stage 1: per-block exclusive scan (+ dinv fused) ----------------
__global__ __launch_bounds__(256) void k_scan1(const int* __restrict__ deg, int* __restrict__ excl,
                                               int* __restrict__ bsums, float* __restrict__ dinv, int n) {
    __shared__ int tmp[256];
    int i = blockIdx.x * 256 + threadIdx.x;
    int v = (i < n) ? deg[i] : 0;
    if (i < n) dinv[i] = rsqrtf((float)v + 1.0f);
    tmp[threadIdx.x] = v;
    __syncthreads();
    for (int offs = 1; offs < 256; offs <<= 1) {
        int t = (threadIdx.x >= offs) ? tmp[threadIdx.x - offs] : 0;
        __syncthreads();
        tmp[threadIdx.x] += t;
        __syncthreads();
    }
    if (i < n) excl[i] = tmp[threadIdx.x] - v;
    if (threadIdx.x == 255) bsums[blockIdx.x] = tmp[255];
}

// ---------------- scan stage 2: scan the block sums (nb <= 512) ----------------
__global__ __launch_bounds__(512) void k_scan2(int* __restrict__ bsums, int nb) {
    __shared__ int tmp[512];
    int v = (threadIdx.x < nb) ? bsums[threadIdx.x] : 0;
    tmp[threadIdx.x] = v;
    __syncthreads();
    for (int offs = 1; offs < 512; offs <<= 1) {
        int t = (threadIdx.x >= offs) ? tmp[threadIdx.x - offs] : 0;
        __syncthreads();
        tmp[threadIdx.x] += t;
        __syncthreads();
    }
    if (threadIdx.x < nb) bsums[threadIdx.x] = tmp[threadIdx.x] - v;  // exclusive
}

// ---------------- scan stage 3: add block offsets, init cursor ----------------
__global__ __launch_bounds__(256) void k_scan3(int* __restrict__ row_start, int* __restrict__ cursor,
                                               const int* __restrict__ bsums, int n, int E) {
    int i = blockIdx.x * 256 + threadIdx.x;
    if (i < n) {
        int rs = row_start[i] + bsums[blockIdx.x];
        row_start[i] = rs;
        cursor[i] = rs;
    }
    if (blockIdx.x == 0 && threadIdx.x == 0) row_start[n] = E;
}

// ---------------- CSR fill (counting-sort placement) ----------------
__global__ __launch_bounds__(256) void k_fill(const int* __restrict__ ei, int E,
                                              int* __restrict__ cursor, int* __restrict__ ssrc) {
    int e = blockIdx.x * 256 + threadIdx.x;
    if (e < E) {
        int s = ei[e];
        int d = ei[E + e];
        int p = atomicAdd(&cursor[d], 1);
        ssrc[p] = s;
    }
}

// ---------------- h' = (x @ W) * dinv[row] ----------------
// One wave = 8 rows; lane = output column (HID=64). W staged in LDS (32 KB).
// 8 independent broadcast float4 loads per k-step give ILP without the
// VGPR bloat of round-5's unroll-8 (196 VGPR -> 10% occupancy).
__global__ __launch_bounds__(256) void k_gemm(const float* __restrict__ x, const float* __restrict__ W,
                                              const float* __restrict__ dinv, float* __restrict__ h, int n) {
    __shared__ float Ws[INC * HID];
    for (int i = threadIdx.x; i < INC * HID / 4; i += 256)
        ((float4*)Ws)[i] = ((const float4*)W)[i];
    __syncthreads();

    int wave = threadIdx.x >> 6;
    int lane = threadIdx.x & 63;
    int row0 = (blockIdx.x * 4 + wave) * 8;
    if (row0 >= n) return;

    if (row0 + 8 <= n) {
        float acc[8];
        #pragma unroll
        for (int r = 0; r < 8; ++r) acc[r] = 0.f;
        const float* xp = x + (size_t)row0 * INC;
        for (int k = 0; k < INC; k += 4) {
            float4 xv[8];
            #pragma unroll
            for (int r = 0; r < 8; ++r)
                xv[r] = *(const float4*)(xp + (size_t)r * INC + k);
            float w0 = Ws[(k + 0) * HID + lane];
            float w1 = Ws[(k + 1) * HID + lane];
            float w2 = Ws[(k + 2) * HID + lane];
            float w3 = Ws[(k + 3) * HID + lane];
            #pragma unroll
            for (int r = 0; r < 8; ++r)
                acc[r] += xv[r].x * w0 + xv[r].y * w1 + xv[r].z * w2 + xv[r].w * w3;
        }
        #pragma unroll
        for (int r = 0; r < 8; ++r)
            h[(size_t)(row0 + r) * HID + lane] = acc[r] * dinv[row0 + r];
    } else {
        for (int r = 0; r < n - row0; ++r) {
            float a = 0.f;
            const float* xr = x + (size_t)(row0 + r) * INC;
            for (int k = 0; k < INC; ++k) a += xr[k] * Ws[k * HID + lane];
            h[(size_t)(row0 + r) * HID + lane] = a * dinv[row0 + r];
        }
    }
}

// ---------------- gather + self-loop + bias + PReLU ----------------
// 16 lanes per node, each lane owns a float4 chunk of the 64-wide row.
__global__ __launch_bounds__(256) void k_gather(const float* __restrict__ h, const int* __restrict__ row_start,
                                                const int* __restrict__ ssrc, const float* __restrict__ dinv,
                                                const float* __restrict__ bias, const float* __restrict__ pw,
                                                float* __restrict__ out, int n) {
    int g = blockIdx.x * 16 + (threadIdx.x >> 4);
    if (g >= n) return;
    int c = (threadIdx.x & 15) * 4;

    int e = row_start[g];
    int e1 = row_start[g + 1];
    float ax = 0.f, ay = 0.f, az = 0.f, aw = 0.f;

    if (e + 4 <= e1) {
        int s0 = ssrc[e], s1 = ssrc[e + 1], s2 = ssrc[e + 2], s3 = ssrc[e + 3];
        for (;;) {
            float4 h0 = *(const float4*)(h + (size_t)s0 * HID + c);
            float4 h1 = *(const float4*)(h + (size_t)s1 * HID + c);
            float4 h2 = *(const float4*)(h + (size_t)s2 * HID + c);
            float4 h3 = *(const float4*)(h + (size_t)s3 * HID + c);
            e += 4;
            if (e + 4 <= e1) {  // prefetch next quad's indices before the adds
                int t0 = ssrc[e], t1 = ssrc[e + 1], t2 = ssrc[e + 2], t3 = ssrc[e + 3];
                ax += (h0.x + h1.x) + (h2.x + h3.x);
                ay += (h0.y + h1.y) + (h2.y + h3.y);
                az += (h0.z + h1.z) + (h2.z + h3.z);
                aw += (h0.w + h1.w) + (h2.w + h3.w);
                s0 = t0; s1 = t1; s2 = t2; s3 = t3;
            } else {
                ax += (h0.x + h1.x) + (h2.x + h3.x);
                ay += (h0.y + h1.y) + (h2.y + h3.y);
                az += (h0.z + h1.z) + (h2.z + h3.z);
                aw += (h0.w + h1.w) + (h2.w + h3.w);
                break;
            }
        }
    }
    for (; e < e1; ++e) {
        int s = ssrc[e];
        float4 hv = *(const float4*)(h + (size_t)s * HID + c);
        ax += hv.x; ay += hv.y; az += hv.z; aw += hv.w;
    }

    float me = dinv[g];
    float4 hs = *(const float4*)(h + (size_t)g * HID + c);
    float4 bb = *(const float4*)(bias + c);
    float4 pp = *(const float4*)(pw + c);

    float vx = (ax + hs.x) * me + bb.x;
    float vy = (ay + hs.y) * me + bb.y;
    float vz = (az + hs.z) * me + bb.z;
    float vw = (aw + hs.w) * me + bb.w;

    float4 o;
    o.x = vx >= 0.f ? vx : pp.x * vx;
    o.y = vy >= 0.f ? vy : pp.y * vy;
    o.z = vz >= 0.f ? vz : pp.z * vz;
    o.w = vw >= 0.f ? vw : pp.w * vw;
    *(float4*)(out + (size_t)g * HID + c) = o;
}

extern "C" void kernel_launch(void* const* d_in, const int* in_sizes, int n_in,
                              void* d_out, int out_size, void* d_ws, size_t ws_size,
                              hipStream_t stream) {
    const float* x    = (const float*)d_in[0];
    const int*   ei   = (const int*)d_in[1];   // int32 per harness contract (2 x E)
    const float* W    = (const float*)d_in[2];
    const float* bias = (const float*)d_in[3];
    const float* pw   = (const float*)d_in[4];
    float* out        = (float*)d_out;

    int n = in_sizes[0] / INC;
    int E = in_sizes[1] / 2;

    // workspace carve-out (256B aligned regions)
    char* ws = (char*)d_ws;
    size_t off = 0;
    auto carve = [&](size_t bytes) -> void* {
        void* p = ws + off;
        off = (off + bytes + 255) & ~(size_t)255;
        return p;
    };
    float* h        = (float*)carve((size_t)n * HID * sizeof(float));
    int*   deg      = (int*)carve((size_t)n * sizeof(int));
    float* dinv     = (float*)carve((size_t)n * sizeof(float));
    int*   row_start= (int*)carve(((size_t)n + 1) * sizeof(int));
    int*   cursor   = (int*)carve((size_t)n * sizeof(int));
    int*   ssrc     = (int*)carve((size_t)E * sizeof(int));
    int    nb       = (n + 255) / 256;
    int*   bsums    = (int*)carve((size_t)nb * sizeof(int));
    (void)ws_size; (void)n_in; (void)out_size;

    int gE = (E + 255) / 256;
    int gN = nb;
    int gG = (n + 31) / 32;   // k_gemm: 32 rows per block (4 waves x 8 rows)
    int gR = (n + 15) / 16;   // k_gather: 16 nodes per block

    hipMemsetAsync(deg, 0, (size_t)n * sizeof(int), stream);
    k_count<<<gE, 256, 0, stream>>>(ei, E, deg);
    k_scan1<<<gN, 256, 0, stream>>>(deg, row_start, bsums, dinv, n);
    k_scan2<<<1, 512, 0, stream>>>(bsums, nb);
    k_scan3<<<gN, 256, 0, stream>>>(row_start, cursor, bsums, n, E);
    k_fill<<<gE, 256, 0, stream>>>(ei, E, cursor, ssrc);
    k_gemm<<<gG, 256, 0, stream>>>(x, W, dinv, h, n);
    k_gather<<<gR, 256, 0, stream>>>(h, row_start, ssrc, dinv, bias, pw, out, n);
}